// Round 4
// baseline (721.432 us; speedup 1.0000x reference)
//
#include <hip/hip_runtime.h>

// Problem constants
#define B_   32
#define N_   512
#define C_   768
#define H_   12
#define D_   64
#define HID_ 3072
#define BN_  (B_*N_)      // 16384 rows

typedef unsigned short u16;
typedef __attribute__((ext_vector_type(8))) short  short8;   // 8 bf16 (4 VGPRs)
typedef __attribute__((ext_vector_type(4))) float  float4v;  // 4 fp32 acc
typedef __attribute__((ext_vector_type(4))) int    int4v;

__device__ __forceinline__ u16 f32_to_bf16(float f) {
  unsigned u = __builtin_bit_cast(unsigned, f);
  u += 0x7fffu + ((u >> 16) & 1u);   // RNE
  return (u16)(u >> 16);
}

// exact-GELU via A&S 7.1.26 erf approx, |err| < 1.5e-7 (below bf16 ulp)
__device__ __forceinline__ float gelu_f(float x) {
  float z = fabsf(x) * 0.70710678118654752f;
  float t = __builtin_amdgcn_rcpf(1.0f + 0.3275911f * z);
  float p = t * (0.254829592f +
            t * (-0.284496736f +
            t * (1.421413741f +
            t * (-1.453152027f +
            t * 1.061405429f))));
  float e = __expf(-z * z);
  float er = 1.0f - p * e;                 // erf(z)
  er = (x < 0.0f) ? -er : er;
  return 0.5f * x * (1.0f + er);
}

// async global->LDS, 16B per lane
__device__ __forceinline__ void load_lds16(const u16* g, u16* l) {
  __builtin_amdgcn_global_load_lds(
      (const __attribute__((address_space(1))) unsigned int*)g,
      (__attribute__((address_space(3))) unsigned int*)l,
      16, 0, 0);
}

// inline-asm ds_read_b128 (invisible to the waitcnt pass; caller pairs with
// s_waitcnt lgkmcnt(0) + sched_barrier(0) before consuming -- rule #18).
__device__ __forceinline__ short8 ds_read_b128a(unsigned byte_off) {
  int4v r;
  asm volatile("ds_read_b128 %0, %1" : "=v"(r) : "v"(byte_off));
  return __builtin_bit_cast(short8, r);
}

__device__ __forceinline__ unsigned lds_addr(const u16* p) {
  return (unsigned)(size_t)(const __attribute__((address_space(3))) u16*)p;
}

// ---------------- merged weight cast f32 -> bf16 (dst buffers contiguous) ----
#define NW0_ (3 * C_ * C_)
#define NW1_ (NW0_ + C_ * C_)
#define NW2_ (NW1_ + HID_ * C_)
#define NW3_ (NW2_ + C_ * HID_)
__global__ __launch_bounds__(256)
void cast4_kernel(const float* __restrict__ s0, const float* __restrict__ s1,
                  const float* __restrict__ s2, const float* __restrict__ s3,
                  u16* __restrict__ dst) {
  int i = blockIdx.x * 256 + threadIdx.x;
  const float* s; int j;
  if (i < NW0_)      { s = s0; j = i; }
  else if (i < NW1_) { s = s1; j = i - NW0_; }
  else if (i < NW2_) { s = s2; j = i - NW1_; }
  else               { s = s3; j = i - NW2_; }
  dst[i] = f32_to_bf16(s[j]);
}

// ---------------- LayerNorm (row = 768 fp32) -> bf16 ----------------
__global__ __launch_bounds__(256)
void ln_kernel(const float* __restrict__ x, const float* __restrict__ w,
               const float* __restrict__ bias, u16* __restrict__ out) {
  const int row = blockIdx.x;
  const int tid = threadIdx.x;
  const float* xr = x + (size_t)row * C_;
  float v0 = xr[tid], v1 = xr[tid + 256], v2 = xr[tid + 512];
  float s = v0 + v1 + v2;
  float q = v0*v0 + v1*v1 + v2*v2;
#pragma unroll
  for (int off = 1; off < 64; off <<= 1) { s += __shfl_xor(s, off); q += __shfl_xor(q, off); }
  __shared__ float red[8];
  int wave = tid >> 6, lane = tid & 63;
  if (lane == 0) { red[wave] = s; red[4 + wave] = q; }
  __syncthreads();
  s = red[0] + red[1] + red[2] + red[3];
  q = red[4] + red[5] + red[6] + red[7];
  float mean = s * (1.0f / C_);
  float var  = q * (1.0f / C_) - mean * mean;
  float rstd = rsqrtf(var + 1e-5f);
  u16* orow = out + (size_t)row * C_;
  orow[tid]       = f32_to_bf16((v0 - mean) * rstd * w[tid]       + bias[tid]);
  orow[tid + 256] = f32_to_bf16((v1 - mean) * rstd * w[tid + 256] + bias[tid + 256]);
  orow[tid + 512] = f32_to_bf16((v2 - mean) * rstd * w[tid + 512] + bias[tid + 512]);
}

// ------- V transpose: qkv unified [BN, 3C] V-cols -> Vt[B*H, D, N] --------------
__global__ __launch_bounds__(256)
void transpose_v(const u16* __restrict__ qkv, u16* __restrict__ vt) {
  __shared__ alignas(16) u16 T[64 * 72];
  const int nt = blockIdx.x, bh = blockIdx.y;
  const int b = bh / H_, h = bh % H_;
  const int tid = threadIdx.x;
  const size_t rs3 = 3 * C_;
  const int r = tid >> 2, dc = (tid & 3) * 16;
  const u16* src = qkv + (size_t)(b * N_ + nt * 64 + r) * rs3 + 2 * C_ + h * D_ + dc;
  short8 a0 = *(const short8*)src;
  short8 a1 = *(const short8*)(src + 8);
#pragma unroll
  for (int j = 0; j < 8; j++) T[(dc + j) * 72 + r] = (u16)a0[j];
#pragma unroll
  for (int j = 0; j < 8; j++) T[(dc + 8 + j) * 72 + r] = (u16)a1[j];
  __syncthreads();
  const int d = tid >> 2, nc = (tid & 3) * 16;
  u16* dst = vt + ((size_t)(b * H_ + h) * D_ + d) * N_ + nt * 64 + nc;
  *(short8*)dst       = *(const short8*)&T[d * 72 + nc];
  *(short8*)(dst + 8) = *(const short8*)&T[d * 72 + nc + 8];
}

// ================= 128x128x(BK=64) bf16 NT GEMM (round-0 proven core) ============
// CONTROL arm: qkv, proj.
template <int EPI>
__device__ __forceinline__ void gemm_core128(const u16* __restrict__ A, const u16* __restrict__ W,
                                             int N, int K,
                                             const float* __restrict__ bias,
                                             const float* __restrict__ resid,
                                             u16* __restrict__ out_bf, float* __restrict__ out_f) {
  __shared__ alignas(16) u16 As[128 * 64];
  __shared__ alignas(16) u16 Ws[128 * 64];
  const int tid  = threadIdx.x;
  const int wave = tid >> 6;
  const int lane = tid & 63;
  const int quad = lane >> 4;
  const int l15  = lane & 15;

  const int nx    = gridDim.x;
  const int lin   = blockIdx.y * nx + blockIdx.x;
  const int total = nx * gridDim.y;
  const int v     = (lin & 7) * (total >> 3) + (lin >> 3);
  const int m0 = (v / nx) << 7;
  const int n0 = (v % nx) << 7;

  const int wm = (wave >> 1) * 64;
  const int wn = (wave & 1) * 64;

  float4v acc[4][4];
#pragma unroll
  for (int i = 0; i < 4; i++)
#pragma unroll
    for (int j = 0; j < 4; j++) acc[i][j] = (float4v){0.f, 0.f, 0.f, 0.f};

  const int c0   = wave * 4;
  const int srow = lane >> 3;
  const int gcol = ((lane & 7) ^ srow) * 8;
  const u16* Ag[4];
  const u16* Wg[4];
#pragma unroll
  for (int j = 0; j < 4; j++) {
    const int row = (c0 + j) * 8 + srow;
    Ag[j] = A + (size_t)(m0 + row) * K + gcol;
    Wg[j] = W + (size_t)(n0 + row) * K + gcol;
  }

  for (int k0 = 0; k0 < K; k0 += 64) {
    __syncthreads();
#pragma unroll
    for (int j = 0; j < 4; j++) load_lds16(Ag[j] + k0, &As[(c0 + j) * 512]);
#pragma unroll
    for (int j = 0; j < 4; j++) load_lds16(Wg[j] + k0, &Ws[(c0 + j) * 512]);
    __syncthreads();

    short8 af[4][2], bf[4][2];
#pragma unroll
    for (int mi = 0; mi < 4; mi++)
#pragma unroll
      for (int ks = 0; ks < 2; ks++) {
        const int swz = ((ks * 4 + quad) ^ (l15 & 7)) * 8;
        af[mi][ks] = *(const short8*)&As[(wm + mi * 16 + l15) * 64 + swz];
        bf[mi][ks] = *(const short8*)&Ws[(wn + mi * 16 + l15) * 64 + swz];
      }
#pragma unroll
    for (int ks = 0; ks < 2; ks++)
#pragma unroll
      for (int mi = 0; mi < 4; mi++)
#pragma unroll
        for (int ni = 0; ni < 4; ni++)
          acc[mi][ni] = __builtin_amdgcn_mfma_f32_16x16x32_bf16(af[mi][ks], bf[ni][ks], acc[mi][ni], 0, 0, 0);
  }

#pragma unroll
  for (int mi = 0; mi < 4; mi++) {
#pragma unroll
    for (int r = 0; r < 4; r++) {
      const int row = m0 + wm + mi * 16 + quad * 4 + r;
#pragma unroll
      for (int ni = 0; ni < 4; ni++) {
        const int col = n0 + wn + ni * 16 + l15;
        float v2 = acc[mi][ni][r];
        if (EPI == 0) {
          out_bf[(size_t)row * N + col] = f32_to_bf16(v2);
        } else if (EPI == 1) {
          out_bf[(size_t)row * N + col] = f32_to_bf16(gelu_f(v2 + bias[col]));
        } else if (EPI == 2) {
          out_f[(size_t)row * N + col] = 2.0f * (v2 + bias[col]);
        } else {
          out_f[(size_t)row * N + col] = v2 + bias[col] + resid[(size_t)row * N + col];
        }
      }
    }
  }
}

// ========== 256x256x(BK=64) QUADRANT-PIPELINED bf16 NT GEMM (v4) =================
// Round-3 counters showed pure serialization: LDS-read bursts and MFMA bursts
// alternate (all pipes <30% busy).  v4 issues the ds_reads of quadrant q+1 UNDER
// the MFMA of quadrant q, so the LDS pipe drains concurrently with the matrix pipe.
// Quadrant order q0:(M0,N0)=af0*bf0  q1:(M1,N0)=af1*bf0  q2:(M0,N1)=af0*bf1
// q3:(M1,N1)=af1*bf1 gives single-buffered frags (each frag's next-tile read
// issues after its last consume).  2 barriers per K-tile:
//   SBAR#1 (q2, after lgkm wait => all waves' reads of buf complete) -> STAGE t+2
//   SBAR#2 (q3, after counted vmcnt(8) => tile t+1 resident) -> read t+1 frags
// vmcnt(8) drains loads issued a full tile (~4 quadrants ~2500cyc) earlier.
#define SBAR()                                   \
  do {                                           \
    asm volatile("" ::: "memory");               \
    __builtin_amdgcn_s_barrier();                \
    asm volatile("" ::: "memory");               \
  } while (0)

#define WAITL()                                              \
  do {                                                       \
    asm volatile("s_waitcnt lgkmcnt(0)" ::: "memory");       \
    __builtin_amdgcn_sched_barrier(0);                       \
  } while (0)

#define SB0() __builtin_amdgcn_sched_barrier(0)

#define STG_A(BUF, HH, KT)                                                    \
  do {                                                                        \
    const u16* _s = aS + (size_t)(HH) * 128 * (size_t)K + (size_t)(KT) * 64;  \
    load_lds16(_s, &LA[BUF][HH][wave * 1024]);                                \
    load_lds16(_s + 8 * (size_t)K, &LA[BUF][HH][wave * 1024 + 512]);          \
  } while (0)

#define STG_B(BUF, HH, KT)                                                    \
  do {                                                                        \
    const u16* _s = bS + (size_t)(HH) * 128 * (size_t)K + (size_t)(KT) * 64;  \
    load_lds16(_s, &LB[BUF][HH][wave * 1024]);                                \
    load_lds16(_s + 8 * (size_t)K, &LB[BUF][HH][wave * 1024 + 512]);          \
  } while (0)

// 8 reads: A-frags for M-quadrant MI0 (rows (MI0+mi)*16+l15 of this wave's half)
#define RD_AF(DST, AT, MI0)                                                       \
  do {                                                                            \
    _Pragma("unroll") for (int mi = 0; mi < 4; ++mi) {                            \
      DST[mi][0] = ds_read_b128a((AT) + ((((MI0) + mi) * 1024u + rb + sw0) << 1));\
      DST[mi][1] = ds_read_b128a((AT) + ((((MI0) + mi) * 1024u + rb + sw1) << 1));\
    }                                                                             \
  } while (0)

// 4 reads: B-frags for N-pair NI0 (rows brow0+(NI0+ni)*16+l15 of this wave's half)
#define RD_BF(DST, BT, NI0)                                                       \
  do {                                                                            \
    _Pragma("unroll") for (int ni = 0; ni < 2; ++ni) {                            \
      DST[ni][0] = ds_read_b128a((BT) + ((((NI0) + ni) * 1024u + rb + sw0) << 1));\
      DST[ni][1] = ds_read_b128a((BT) + ((((NI0) + ni) * 1024u + rb + sw1) << 1));\
    }                                                                             \
  } while (0)

#define MMQ(MI0, NI0, AF, BF)                                                 \
  do {                                                                        \
    __builtin_amdgcn_s_setprio(1);                                            \
    _Pragma("unroll") for (int ks = 0; ks < 2; ++ks)                          \
      _Pragma("unroll") for (int mi = 0; mi < 4; ++mi)                        \
        _Pragma("unroll") for (int ni = 0; ni < 2; ++ni)                      \
          acc[(MI0) + mi][(NI0) + ni] =                                       \
              __builtin_amdgcn_mfma_f32_16x16x32_bf16(                        \
                  AF[mi][ks], BF[ni][ks], acc[(MI0) + mi][(NI0) + ni], 0, 0, 0);\
    __builtin_amdgcn_s_setprio(0);                                            \
  } while (0)

template <int EPI>
__device__ __forceinline__ void gemm256_qp(const u16* __restrict__ A, const u16* __restrict__ W,
                                           int N, int K,
                                           const float* __restrict__ bias,
                                           const float* __restrict__ resid,
                                           u16* __restrict__ out_bf, float* __restrict__ out_f) {
  __shared__ alignas(16) u16 LA[2][2][8192];   // [buf][half][128*64]  64 KiB
  __shared__ alignas(16) u16 LB[2][2][8192];   //                      64 KiB
  const int tid  = threadIdx.x;
  const int wave = tid >> 6;
  const int lane = tid & 63;
  const int quad = lane >> 4;
  const int l15  = lane & 15;
  const int l7   = l15 & 7;
  const int wm   = wave >> 2;        // 0..1 -> M offset wm*128
  const int wn   = wave & 3;         // 0..3 -> N offset wn*64
  const int bhalf = wn >> 1;
  const int brow0 = (wn & 1) * 64;

  // XCD-aware bijective swizzle (all grids here are %8==0)
  const int nx    = gridDim.x;
  const int lin   = blockIdx.y * nx + blockIdx.x;
  const int total = nx * gridDim.y;
  const int v     = (lin & 7) * (total >> 3) + (lin >> 3);
  const int m0 = (v / nx) << 8;
  const int n0 = (v % nx) << 8;

  const int T = K >> 6;              // K-tiles (12 or 48 here)

  float4v acc[8][4];
#pragma unroll
  for (int i = 0; i < 8; i++)
#pragma unroll
    for (int j = 0; j < 4; j++) acc[i][j] = (float4v){0.f, 0.f, 0.f, 0.f};

  // staging source (per lane); global K-group pre-swizzled so LDS stays linear
  const int srow = lane >> 3;
  const int scol = ((lane & 7) ^ srow) << 3;
  const int rowc = wave * 16 + srow;
  const u16* aS = A + (size_t)(m0 + rowc) * K + scol;
  const u16* bS = W + (size_t)(n0 + rowc) * K + scol;

  // LDS byte-address bases for asm ds_reads
  const unsigned laBase = lds_addr(&LA[0][0][0]);
  const unsigned lbBase = lds_addr(&LB[0][0][0]);
  const unsigned sw0 = (unsigned)((quad ^ l7) << 3);
  const unsigned sw1 = (unsigned)(((4 + quad) ^ l7) << 3);
  const unsigned rb  = (unsigned)(l15 * 64);
  const unsigned aW  = laBase + (unsigned)(wm * 16384);
  const unsigned bW  = lbBase + (unsigned)(bhalf * 16384 + brow0 * 128);

  short8 af0_[4][2], af1_[4][2];     // A frags for M-quadrants 0 / 1
  short8 bf0_[2][2], bf1_[2][2];     // B frags for N-pairs 0 / 1

  // ---- prologue: stage t0,t1 (16 loads); drain t0 (leave 8); read t0 q0 frags ----
  STG_A(0, 0, 0); STG_A(0, 1, 0);
  STG_B(0, 0, 0); STG_B(0, 1, 0);
  STG_A(1, 0, 1); STG_A(1, 1, 1);
  STG_B(1, 0, 1); STG_B(1, 1, 1);
  asm volatile("s_waitcnt vmcnt(8)" ::: "memory");
  SBAR();
  RD_AF(af0_, aW, 0);
  RD_BF(bf0_, bW, 0);

  for (int kt = 0; kt < T; ++kt) {
    const int buf = kt & 1;
    const unsigned aT  = aW + (unsigned)(buf * 32768);
    const unsigned bT  = bW + (unsigned)(buf * 32768);
    const unsigned aT2 = aW + (unsigned)((buf ^ 1) * 32768);
    const unsigned bT2 = bW + (unsigned)((buf ^ 1) * 32768);
    // ---- q0: consume af0*bf0; issue af1 reads (drain under MFMA) ----
    WAITL();
    RD_AF(af1_, aT, 4);
    SB0();
    MMQ(0, 0, af0_, bf0_);
    // ---- q1: consume af1*bf0; issue bf1 reads ----
    WAITL();
    RD_BF(bf1_, bT, 2);
    SB0();
    MMQ(4, 0, af1_, bf0_);
    // ---- q2: consume af0*bf1; all buf reads complete -> barrier -> stage t+2 ----
    WAITL();
    SBAR();
    if (kt + 2 < T) {
      STG_A(buf, 0, kt + 2); STG_A(buf, 1, kt + 2);
      STG_B(buf, 0, kt + 2); STG_B(buf, 1, kt + 2);
    }
    SB0();
    MMQ(0, 2, af0_, bf1_);
    // ---- q3: consume af1*bf1; counted vmcnt -> barrier -> read t+1 q0 frags ----
    if (kt + 2 < T) { asm volatile("s_waitcnt vmcnt(8)" ::: "memory"); }
    else            { asm volatile("s_waitcnt vmcnt(0)" ::: "memory"); }
    SBAR();
    if (kt + 1 < T) {
      RD_AF(af0_, aT2, 0);
      RD_BF(bf0_, bT2, 0);
    }
    SB0();
    MMQ(4, 2, af1_, bf1_);
  }

  // ---- epilogue ----
#pragma unroll
  for (int mi = 0; mi < 8; ++mi) {
#pragma unroll
    for (int r = 0; r < 4; ++r) {
      const int row = m0 + wm * 128 + mi * 16 + quad * 4 + r;
#pragma unroll
      for (int ni = 0; ni < 4; ++ni) {
        const int col = n0 + wn * 64 + ni * 16 + l15;
        float v2 = acc[mi][ni][r];
        if (EPI == 0) {
          out_bf[(size_t)row * N + col] = f32_to_bf16(v2);
        } else if (EPI == 1) {
          out_bf[(size_t)row * N + col] = f32_to_bf16(gelu_f(v2 + bias[col]));
        } else if (EPI == 2) {
          out_f[(size_t)row * N + col] = 2.0f * (v2 + bias[col]);
        } else {
          out_f[(size_t)row * N + col] = v2 + bias[col] + resid[(size_t)row * N + col];
        }
      }
    }
  }
}

#undef SBAR
#undef WAITL
#undef SB0
#undef STG_A
#undef STG_B
#undef RD_AF
#undef RD_BF
#undef MMQ

// control arm: proven 128^2 core
__global__ __launch_bounds__(256, 3)
void gemm_qkv(const u16* __restrict__ A, const u16* __restrict__ W, int N, int K,
              u16* __restrict__ out_bf) {
  gemm_core128<0>(A, W, N, K, nullptr, nullptr, out_bf, nullptr);
}
__global__ __launch_bounds__(256, 3)
void gemm_proj2x(const u16* __restrict__ A, const u16* __restrict__ W, int N, int K,
                 const float* __restrict__ bias, float* __restrict__ out_f) {
  gemm_core128<2>(A, W, N, K, bias, nullptr, nullptr, out_f);
}
// treatment arm: quadrant-pipelined 256^2
__global__ __launch_bounds__(512, 2)
void gemm_fc1gelu(const u16* __restrict__ A, const u16* __restrict__ W, int N, int K,
                  const float* __restrict__ bias, u16* __restrict__ out_bf) {
  gemm256_qp<1>(A, W, N, K, bias, nullptr, out_bf, nullptr);
}
__global__ __launch_bounds__(512, 2)
void gemm_fc2res(const u16* __restrict__ A, const u16* __restrict__ W, int N, int K,
                 const float* __restrict__ bias, const float* __restrict__ resid,
                 float* __restrict__ out_f) {
  gemm256_qp<3>(A, W, N, K, bias, resid, nullptr, out_f);
}

// ---------------- flash attention v3 ---------------------------------------------
__global__ __launch_bounds__(256)
void attn_kernel(const u16* __restrict__ qkv, const u16* __restrict__ vt,
                 u16* __restrict__ o) {
  __shared__ alignas(16) u16 Ks[64 * 64];
  __shared__ alignas(16) u16 Vs[64 * 64];
  __shared__ alignas(16) u16 Ps[8][16 * 64];
  const int tid  = threadIdx.x;
  const int wave = tid >> 6, lane = tid & 63;
  const int quad = lane >> 4, l15 = lane & 15;
  const int lin = blockIdx.x;
  const int bh = lin % 384, qt = lin / 384;
  const int b = bh / H_, h = bh % H_;
  const size_t rs3 = 3 * C_;

  short8 qf[2][2];
#pragma unroll
  for (int st = 0; st < 2; st++) {
    const int qrow = b * N_ + qt * 128 + st * 64 + wave * 16 + l15;
    const u16* qp = qkv + (size_t)qrow * rs3 + h * D_ + quad * 8;
    qf[st][0] = *(const short8*)qp;
    qf[st][1] = *(const short8*)(qp + 32);
  }

  const int srow = lane >> 3;
  const int gcol = ((lane & 7) ^ srow) * 8;
  const int ch0 = wave * 2, ch1 = wave * 2 + 1;
  const u16* kg0 = qkv + (size_t)(b * N_ + ch0 * 8 + srow) * rs3 + C_ + h * D_ + gcol;
  const u16* kg1 = qkv + (size_t)(b * N_ + ch1 * 8 + srow) * rs3 + C_ + h * D_ + gcol;
  const u16* vg0 = vt + ((size_t)bh * D_ + ch0 * 8 + srow) * N_ + gcol;
  const u16* vg1 = vt + ((size_t)bh * D_ + ch1 * 8 + srow) * N_ + gcol;

  float m[2][4], l[2][4];
  float4v oacc[2][4];
#pragma unroll
  for (int st = 0; st < 2; st++)
#pragma unroll
    for (int r = 0; r < 4; r++) { m[st][r] = -1e30f; l[st][r] = 0.f; }
#pragma unroll
  for (int st = 0; st < 2; st++)
#pragma unroll
    for (int ni = 0; ni < 4; ni++) oacc[st][ni] = (float4v){0.f, 0.f, 0.f, 0.f};

  for (int kt = 0; kt < 8; ++kt) {
    __syncthreads();
    load_lds16(kg0 + (size_t)(kt * 64) * rs3, &Ks[ch0 * 512]);
    load_lds16(kg1 + (size_t)(kt * 64) * rs3, &Ks[ch1 * 512]);
    load_lds16(vg0 + kt * 64, &Vs[ch0 * 512]);
    load_lds16(vg1 + kt * 64, &Vs[ch1 * 512]);
    __syncthreads();

    short8 kf[4][2];
#pragma unroll
    for (int ni = 0; ni < 4; ni++)
#pragma unroll
      for (int ks = 0; ks < 2; ks++)
        kf[ni][ks] = *(const short8*)&Ks[(ni * 16 + l15) * 64 + ((ks * 4 + quad) ^ (l15 & 7)) * 8];

#pragma unroll
    for (int st = 0; st < 2; st++) {
      u16* myPs = Ps[wave * 2 + st];
      float4v s[4];
#pragma unroll
      for (int ni = 0; ni < 4; ni++) {
        s[ni] = (float4v){0.f, 0.f, 0.f, 0.f};
        s[ni] = __builtin_amdgcn_mfma_f32_16x16x32_bf16(qf[st][0], kf[ni][0], s[ni], 0, 0, 0);
        s[ni] = __builtin_amdgcn_mfma_f32_16x16x32_bf16(qf[st][1], kf[ni][1], s[ni], 0, 0, 0);
      }

      float mt[4];
#pragma unroll
      for (int r = 0; r < 4; r++)
        mt[r] = 0.125f * fmaxf(fmaxf(s[0][r], s[1][r]), fmaxf(s[2][r], s[3][r]));
#pragma unroll
      for (int off = 1; off < 16; off <<= 1)
#pragma unroll
        for (int r = 0; r < 4; r++) mt[r] = fmaxf(mt[r], __shfl_xor(mt[r], off));

      float alpha[4], mnew[4], rsum[4];
#pragma unroll
      for (int r = 0; r < 4; r++) {
        mnew[r] = fmaxf(m[st][r], mt[r]);
        alpha[r] = __expf(m[st][r] - mnew[r]);
        rsum[r] = 0.f;
      }
#pragma unroll
      for (int ni = 0; ni < 4; ni++)
#pragma unroll
        for (int r = 0; r < 4; r++) {
          float p = __expf(s[ni][r] * 0.125f - mnew[r]);
          rsum[r] += p;
          const int prow = quad * 4 + r;
          const int g = (ni * 2 + (l15 >> 3)) ^ (prow & 7);
          myPs[prow * 64 + g * 8 + (l15 & 7)] = f32_to_bf16(p);
        }
#pragma unroll
      for (int off = 1; off < 16; off <<= 1)
#pragma unroll
        for (int r = 0; r < 4; r++) rsum[r] += __shfl_xor(rsum[r], off);
#pragma unroll
      for (int r = 0; r < 4; r++) { l[st][r] = l[st][r] * alpha[r] + rsum[r]; m[st][r] = mnew[r]; }
#pragma unroll
      for (int ni = 0; ni < 4; ni++)
#pragma unroll
        for (int r = 0; r < 4; r++) oacc[st][ni][r] *= alpha[r];

#pragma unroll
      for (int ks = 0; ks < 2; ks++) {
        const int g = (ks * 4 + quad) ^ (l15 & 7);
        short8 pf = *(const short8*)&myPs[l15 * 64 + g * 8];
#pragma unroll
        for (int ni = 0; ni < 4; ni++) {
          short8 vf = *(const short8*)&Vs[(ni * 16 + l15) * 64 + ((ks * 4 + quad) ^ (l15 & 7)) * 8];
          oacc[st][ni] = __builtin_amdgcn_mfma_f32_16x16x32_bf16(pf, vf, oacc[st][ni], 0, 0, 0);
        }
      }
    }
  }

#pragma unroll
  for (int st = 0; st < 2; st++) {
    float inv[4];
#pragma unroll
    for (int r = 0; r < 4; r++) inv[r] = 1.0f / l[st][r];
#pragma unroll
    for (int ni = 0; ni < 4; ni++)
#pragma unroll
      for (int r = 0; r < 4; r++) {
        int row = b * N_ + qt * 128 + st * 64 + wave * 16 + quad * 4 + r;
        int col = h * D_ + ni * 16 + l15;
        o[(size_t)row * C_ + col] = f32_to_bf16(oacc[st][ni][r] * inv[r]);
      }
  }
}

// ---------------- launch ----------------
extern "C" void kernel_launch(void* const* d_in, const int* in_sizes, int n_in,
                              void* d_out, int out_size, void* d_ws, size_t ws_size,
                              hipStream_t stream) {
  const float* x      = (const float*)d_in[0];
  const float* ln1_w  = (const float*)d_in[1];
  const float* ln1_b  = (const float*)d_in[2];
  const float* qkv_w  = (const float*)d_in[3];
  const float* proj_w = (const float*)d_in[4];
  const float* proj_b = (const float*)d_in[5];
  const float* ln2_w  = (const float*)d_in[6];
  const float* ln2_b  = (const float*)d_in[7];
  const float* fc1_w  = (const float*)d_in[8];
  const float* fc1_b  = (const float*)d_in[9];
  const float* fc2_w  = (const float*)d_in[10];
  const float* fc2_b  = (const float*)d_in[11];
  float* out = (float*)d_out;

  char* ws = (char*)d_ws;
  size_t off = 0;
  auto alloc = [&](size_t bytes) { void* p = ws + off; off += (bytes + 255) & ~255ull; return p; };
  u16* wqkv  = (u16*)alloc((size_t)3 * C_ * C_ * 2);
  u16* wproj = (u16*)alloc((size_t)C_ * C_ * 2);
  u16* wfc1  = (u16*)alloc((size_t)HID_ * C_ * 2);
  u16* wfc2  = (u16*)alloc((size_t)C_ * HID_ * 2);
  u16* wbase = wqkv;   // contiguous (all segment sizes are 256B-multiples)
  u16* regionA = (u16*)alloc((size_t)BN_ * HID_ * 2);  // h | qkv, later o, later act
  float* xnew  = (float*)alloc((size_t)BN_ * C_ * 4);
  u16* h2      = (u16*)alloc((size_t)BN_ * C_ * 2);

  u16* hbuf = regionA;                        // [BN, C]   (dead after QKV)
  u16* qkvb = regionA + (size_t)BN_ * C_;     // [BN, 3C]  (dead after attn)
  u16* obuf = regionA;                        // [BN, C]   overwrites hbuf
  u16* act  = regionA;                        // [BN, HID] overwrites qkv+o
  u16* vtbuf = (u16*)xnew;                    // [B*H, D, N] aliases xnew

  cast4_kernel<<<dim3(NW3_ / 256), 256, 0, stream>>>(qkv_w, proj_w, fc1_w, fc2_w, wbase);

  ln_kernel<<<dim3(BN_), 256, 0, stream>>>(x, ln1_w, ln1_b, hbuf);

  gemm_qkv<<<dim3(3 * C_ / 128, BN_ / 128), 256, 0, stream>>>(hbuf, wqkv, 3 * C_, C_, qkvb);

  transpose_v<<<dim3(N_ / 64, B_ * H_), 256, 0, stream>>>(qkvb, vtbuf);

  attn_kernel<<<dim3((N_ / 128) * B_ * H_), 256, 0, stream>>>(qkvb, vtbuf, obuf);

  gemm_proj2x<<<dim3(C_ / 128, BN_ / 128), 256, 0, stream>>>(obuf, wproj, C_, C_, proj_b, xnew);

  ln_kernel<<<dim3(BN_), 256, 0, stream>>>(xnew, ln2_w, ln2_b, h2);

  gemm_fc1gelu<<<dim3(HID_ / 256, BN_ / 256), 512, 0, stream>>>(h2, wfc1, HID_, C_, fc1_b, act);

  gemm_fc2res<<<dim3(C_ / 256, BN_ / 256), 512, 0, stream>>>(act, wfc2, C_, HID_, fc2_b, xnew, out);
}

// Round 5
// 506.271 us; speedup vs baseline: 1.4250x; 1.4250x over previous
//
#include <hip/hip_runtime.h>

// Problem constants
#define B_   32
#define N_   512
#define C_   768
#define H_   12
#define D_   64
#define HID_ 3072
#define BN_  (B_*N_)      // 16384 rows

typedef unsigned short u16;
typedef __attribute__((ext_vector_type(8))) short  short8;   // 8 bf16 (4 VGPRs)
typedef __attribute__((ext_vector_type(4))) float  float4v;  // 4 fp32 acc
typedef __attribute__((ext_vector_type(4))) float  f4;
typedef __attribute__((ext_vector_type(4))) unsigned short ushort4v;

__device__ __forceinline__ u16 f32_to_bf16(float f) {
  unsigned u = __builtin_bit_cast(unsigned, f);
  u += 0x7fffu + ((u >> 16) & 1u);   // RNE
  return (u16)(u >> 16);
}

// exact-GELU via A&S 7.1.26 erf approx, |err| < 1.5e-7 (below bf16 ulp)
// ~15 VALU vs libm erff's ~40.  Verified passing (absmax 0.03125) rounds 3-4.
__device__ __forceinline__ float gelu_f(float x) {
  float z = fabsf(x) * 0.70710678118654752f;
  float t = __builtin_amdgcn_rcpf(1.0f + 0.3275911f * z);
  float p = t * (0.254829592f +
            t * (-0.284496736f +
            t * (1.421413741f +
            t * (-1.453152027f +
            t * 1.061405429f))));
  float e = __expf(-z * z);
  float er = 1.0f - p * e;                 // erf(z)
  er = (x < 0.0f) ? -er : er;
  return 0.5f * x * (1.0f + er);
}

// async global->LDS, 16B per lane; lds base wave-uniform, lane i lands at base + i*16B
__device__ __forceinline__ void load_lds16(const u16* g, u16* l) {
  __builtin_amdgcn_global_load_lds(
      (const __attribute__((address_space(1))) unsigned int*)g,
      (__attribute__((address_space(3))) unsigned int*)l,
      16, 0, 0);
}

// ---------------- merged weight cast f32 -> bf16 (dst buffers contiguous) ----
#define NW0_ (3 * C_ * C_)
#define NW1_ (NW0_ + C_ * C_)
#define NW2_ (NW1_ + HID_ * C_)
#define NW3_ (NW2_ + C_ * HID_)
__global__ __launch_bounds__(256)
void cast4_kernel(const float* __restrict__ s0, const float* __restrict__ s1,
                  const float* __restrict__ s2, const float* __restrict__ s3,
                  u16* __restrict__ dst) {
  int i = blockIdx.x * 256 + threadIdx.x;
  const float* s; int j;
  if (i < NW0_)      { s = s0; j = i; }
  else if (i < NW1_) { s = s1; j = i - NW0_; }
  else if (i < NW2_) { s = s2; j = i - NW1_; }
  else               { s = s3; j = i - NW2_; }
  dst[i] = f32_to_bf16(s[j]);
}

// ---------------- LayerNorm (row = 768 fp32) -> bf16, wave-per-row ----------------
// G13: float4 loads (16B/lane), shuffle-only reduce (no LDS, no barrier).
// Block = 4 waves = 4 rows; lane handles 12 elems as 3 x float4.
__global__ __launch_bounds__(256)
void ln_kernel(const float* __restrict__ x, const float* __restrict__ w,
               const float* __restrict__ bias, u16* __restrict__ out) {
  const int wave = threadIdx.x >> 6, lane = threadIdx.x & 63;
  const int row  = blockIdx.x * 4 + wave;
  const float* xr = x + (size_t)row * C_;

  f4 v[3];
  float s = 0.f, q = 0.f;
#pragma unroll
  for (int j = 0; j < 3; j++) {
    v[j] = *(const f4*)(xr + j * 256 + lane * 4);
#pragma unroll
    for (int e = 0; e < 4; e++) { s += v[j][e]; q += v[j][e] * v[j][e]; }
  }
#pragma unroll
  for (int off = 1; off < 64; off <<= 1) {
    s += __shfl_xor(s, off);
    q += __shfl_xor(q, off);
  }
  const float mean = s * (1.0f / C_);
  const float var  = q * (1.0f / C_) - mean * mean;
  const float rstd = rsqrtf(var + 1e-5f);

  u16* orow = out + (size_t)row * C_;
#pragma unroll
  for (int j = 0; j < 3; j++) {
    const int c = j * 256 + lane * 4;
    f4 wv = *(const f4*)(w + c);
    f4 bv = *(const f4*)(bias + c);
    ushort4v o;
#pragma unroll
    for (int e = 0; e < 4; e++)
      o[e] = f32_to_bf16((v[j][e] - mean) * rstd * wv[e] + bv[e]);
    *(ushort4v*)(orow + c) = o;   // 8B store
  }
}

// ------- V transpose: qkv unified [BN, 3C] V-cols -> Vt[B*H, D, N] --------------
__global__ __launch_bounds__(256)
void transpose_v(const u16* __restrict__ qkv, u16* __restrict__ vt) {
  __shared__ alignas(16) u16 T[64 * 72];
  const int nt = blockIdx.x, bh = blockIdx.y;
  const int b = bh / H_, h = bh % H_;
  const int tid = threadIdx.x;
  const size_t rs3 = 3 * C_;
  const int r = tid >> 2, dc = (tid & 3) * 16;
  const u16* src = qkv + (size_t)(b * N_ + nt * 64 + r) * rs3 + 2 * C_ + h * D_ + dc;
  short8 a0 = *(const short8*)src;
  short8 a1 = *(const short8*)(src + 8);
#pragma unroll
  for (int j = 0; j < 8; j++) T[(dc + j) * 72 + r] = (u16)a0[j];
#pragma unroll
  for (int j = 0; j < 8; j++) T[(dc + 8 + j) * 72 + r] = (u16)a1[j];
  __syncthreads();
  const int d = tid >> 2, nc = (tid & 3) * 16;
  u16* dst = vt + ((size_t)(b * H_ + h) * D_ + d) * N_ + nt * 64 + nc;
  *(short8*)dst       = *(const short8*)&T[d * 72 + nc];
  *(short8*)(dst + 8) = *(const short8*)&T[d * 72 + nc + 8];
}

// ================= 128x128x(BK=64) bf16 NT GEMM (round-0 proven core) ============
// All four GEMMs.  LDS XOR-swizzled, global_load_lds width-16, XCD-aware swizzle.
// EPI 0: bf16 (QKV)  1: gelu(y+b)->bf16 (FC1)  2: 2*(y+b)->f32 (proj)  3: y+b+res->f32
template <int EPI>
__device__ __forceinline__ void gemm_core128(const u16* __restrict__ A, const u16* __restrict__ W,
                                             int N, int K,
                                             const float* __restrict__ bias,
                                             const float* __restrict__ resid,
                                             u16* __restrict__ out_bf, float* __restrict__ out_f) {
  __shared__ alignas(16) u16 As[128 * 64];
  __shared__ alignas(16) u16 Ws[128 * 64];
  const int tid  = threadIdx.x;
  const int wave = tid >> 6;
  const int lane = tid & 63;
  const int quad = lane >> 4;
  const int l15  = lane & 15;

  const int nx    = gridDim.x;
  const int lin   = blockIdx.y * nx + blockIdx.x;
  const int total = nx * gridDim.y;
  const int v     = (lin & 7) * (total >> 3) + (lin >> 3);
  const int m0 = (v / nx) << 7;
  const int n0 = (v % nx) << 7;

  const int wm = (wave >> 1) * 64;
  const int wn = (wave & 1) * 64;

  float4v acc[4][4];
#pragma unroll
  for (int i = 0; i < 4; i++)
#pragma unroll
    for (int j = 0; j < 4; j++) acc[i][j] = (float4v){0.f, 0.f, 0.f, 0.f};

  const int c0   = wave * 4;
  const int srow = lane >> 3;
  const int gcol = ((lane & 7) ^ srow) * 8;
  const u16* Ag[4];
  const u16* Wg[4];
#pragma unroll
  for (int j = 0; j < 4; j++) {
    const int row = (c0 + j) * 8 + srow;
    Ag[j] = A + (size_t)(m0 + row) * K + gcol;
    Wg[j] = W + (size_t)(n0 + row) * K + gcol;
  }

  for (int k0 = 0; k0 < K; k0 += 64) {
    __syncthreads();
#pragma unroll
    for (int j = 0; j < 4; j++) load_lds16(Ag[j] + k0, &As[(c0 + j) * 512]);
#pragma unroll
    for (int j = 0; j < 4; j++) load_lds16(Wg[j] + k0, &Ws[(c0 + j) * 512]);
    __syncthreads();

    short8 af[4][2], bf[4][2];
#pragma unroll
    for (int mi = 0; mi < 4; mi++)
#pragma unroll
      for (int ks = 0; ks < 2; ks++) {
        const int swz = ((ks * 4 + quad) ^ (l15 & 7)) * 8;
        af[mi][ks] = *(const short8*)&As[(wm + mi * 16 + l15) * 64 + swz];
        bf[mi][ks] = *(const short8*)&Ws[(wn + mi * 16 + l15) * 64 + swz];
      }
#pragma unroll
    for (int ks = 0; ks < 2; ks++)
#pragma unroll
      for (int mi = 0; mi < 4; mi++)
#pragma unroll
        for (int ni = 0; ni < 4; ni++)
          acc[mi][ni] = __builtin_amdgcn_mfma_f32_16x16x32_bf16(af[mi][ks], bf[ni][ks], acc[mi][ni], 0, 0, 0);
  }

#pragma unroll
  for (int mi = 0; mi < 4; mi++) {
#pragma unroll
    for (int r = 0; r < 4; r++) {
      const int row = m0 + wm + mi * 16 + quad * 4 + r;   // C/D: row = quad*4+reg (m89)
#pragma unroll
      for (int ni = 0; ni < 4; ni++) {
        const int col = n0 + wn + ni * 16 + l15;          // C/D: col = lane&15
        float v2 = acc[mi][ni][r];
        if (EPI == 0) {
          out_bf[(size_t)row * N + col] = f32_to_bf16(v2);
        } else if (EPI == 1) {
          out_bf[(size_t)row * N + col] = f32_to_bf16(gelu_f(v2 + bias[col]));
        } else if (EPI == 2) {
          out_f[(size_t)row * N + col] = 2.0f * (v2 + bias[col]);     // x = o + o quirk
        } else {
          out_f[(size_t)row * N + col] = v2 + bias[col] + resid[(size_t)row * N + col];
        }
      }
    }
  }
}

__global__ __launch_bounds__(256, 3)
void gemm_qkv(const u16* __restrict__ A, const u16* __restrict__ W, int N, int K,
              u16* __restrict__ out_bf) {
  gemm_core128<0>(A, W, N, K, nullptr, nullptr, out_bf, nullptr);
}
__global__ __launch_bounds__(256, 3)
void gemm_proj2x(const u16* __restrict__ A, const u16* __restrict__ W, int N, int K,
                 const float* __restrict__ bias, float* __restrict__ out_f) {
  gemm_core128<2>(A, W, N, K, bias, nullptr, nullptr, out_f);
}
__global__ __launch_bounds__(256, 3)
void gemm_fc1gelu(const u16* __restrict__ A, const u16* __restrict__ W, int N, int K,
                  const float* __restrict__ bias, u16* __restrict__ out_bf) {
  gemm_core128<1>(A, W, N, K, bias, nullptr, out_bf, nullptr);
}
__global__ __launch_bounds__(256, 3)
void gemm_fc2res(const u16* __restrict__ A, const u16* __restrict__ W, int N, int K,
                 const float* __restrict__ bias, const float* __restrict__ resid,
                 float* __restrict__ out_f) {
  gemm_core128<3>(A, W, N, K, bias, resid, nullptr, out_f);
}

// ---------------- flash attention v3 ---------------------------------------------
__global__ __launch_bounds__(256)
void attn_kernel(const u16* __restrict__ qkv, const u16* __restrict__ vt,
                 u16* __restrict__ o) {
  __shared__ alignas(16) u16 Ks[64 * 64];
  __shared__ alignas(16) u16 Vs[64 * 64];
  __shared__ alignas(16) u16 Ps[8][16 * 64];
  const int tid  = threadIdx.x;
  const int wave = tid >> 6, lane = tid & 63;
  const int quad = lane >> 4, l15 = lane & 15;
  const int lin = blockIdx.x;
  const int bh = lin % 384, qt = lin / 384;
  const int b = bh / H_, h = bh % H_;
  const size_t rs3 = 3 * C_;

  short8 qf[2][2];
#pragma unroll
  for (int st = 0; st < 2; st++) {
    const int qrow = b * N_ + qt * 128 + st * 64 + wave * 16 + l15;
    const u16* qp = qkv + (size_t)qrow * rs3 + h * D_ + quad * 8;
    qf[st][0] = *(const short8*)qp;
    qf[st][1] = *(const short8*)(qp + 32);
  }

  const int srow = lane >> 3;
  const int gcol = ((lane & 7) ^ srow) * 8;
  const int ch0 = wave * 2, ch1 = wave * 2 + 1;
  const u16* kg0 = qkv + (size_t)(b * N_ + ch0 * 8 + srow) * rs3 + C_ + h * D_ + gcol;
  const u16* kg1 = qkv + (size_t)(b * N_ + ch1 * 8 + srow) * rs3 + C_ + h * D_ + gcol;
  const u16* vg0 = vt + ((size_t)bh * D_ + ch0 * 8 + srow) * N_ + gcol;
  const u16* vg1 = vt + ((size_t)bh * D_ + ch1 * 8 + srow) * N_ + gcol;

  float m[2][4], l[2][4];
  float4v oacc[2][4];
#pragma unroll
  for (int st = 0; st < 2; st++)
#pragma unroll
    for (int r = 0; r < 4; r++) { m[st][r] = -1e30f; l[st][r] = 0.f; }
#pragma unroll
  for (int st = 0; st < 2; st++)
#pragma unroll
    for (int ni = 0; ni < 4; ni++) oacc[st][ni] = (float4v){0.f, 0.f, 0.f, 0.f};

  for (int kt = 0; kt < 8; ++kt) {
    __syncthreads();
    load_lds16(kg0 + (size_t)(kt * 64) * rs3, &Ks[ch0 * 512]);
    load_lds16(kg1 + (size_t)(kt * 64) * rs3, &Ks[ch1 * 512]);
    load_lds16(vg0 + kt * 64, &Vs[ch0 * 512]);
    load_lds16(vg1 + kt * 64, &Vs[ch1 * 512]);
    __syncthreads();

    short8 kf[4][2];
#pragma unroll
    for (int ni = 0; ni < 4; ni++)
#pragma unroll
      for (int ks = 0; ks < 2; ks++)
        kf[ni][ks] = *(const short8*)&Ks[(ni * 16 + l15) * 64 + ((ks * 4 + quad) ^ (l15 & 7)) * 8];

#pragma unroll
    for (int st = 0; st < 2; st++) {
      u16* myPs = Ps[wave * 2 + st];
      float4v s[4];
#pragma unroll
      for (int ni = 0; ni < 4; ni++) {
        s[ni] = (float4v){0.f, 0.f, 0.f, 0.f};
        s[ni] = __builtin_amdgcn_mfma_f32_16x16x32_bf16(qf[st][0], kf[ni][0], s[ni], 0, 0, 0);
        s[ni] = __builtin_amdgcn_mfma_f32_16x16x32_bf16(qf[st][1], kf[ni][1], s[ni], 0, 0, 0);
      }

      float mt[4];
#pragma unroll
      for (int r = 0; r < 4; r++)
        mt[r] = 0.125f * fmaxf(fmaxf(s[0][r], s[1][r]), fmaxf(s[2][r], s[3][r]));
#pragma unroll
      for (int off = 1; off < 16; off <<= 1)
#pragma unroll
        for (int r = 0; r < 4; r++) mt[r] = fmaxf(mt[r], __shfl_xor(mt[r], off));

      float alpha[4], mnew[4], rsum[4];
#pragma unroll
      for (int r = 0; r < 4; r++) {
        mnew[r] = fmaxf(m[st][r], mt[r]);
        alpha[r] = __expf(m[st][r] - mnew[r]);
        rsum[r] = 0.f;
      }
#pragma unroll
      for (int ni = 0; ni < 4; ni++)
#pragma unroll
        for (int r = 0; r < 4; r++) {
          float p = __expf(s[ni][r] * 0.125f - mnew[r]);
          rsum[r] += p;
          const int prow = quad * 4 + r;
          const int g = (ni * 2 + (l15 >> 3)) ^ (prow & 7);
          myPs[prow * 64 + g * 8 + (l15 & 7)] = f32_to_bf16(p);
        }
#pragma unroll
      for (int off = 1; off < 16; off <<= 1)
#pragma unroll
        for (int r = 0; r < 4; r++) rsum[r] += __shfl_xor(rsum[r], off);
#pragma unroll
      for (int r = 0; r < 4; r++) { l[st][r] = l[st][r] * alpha[r] + rsum[r]; m[st][r] = mnew[r]; }
#pragma unroll
      for (int ni = 0; ni < 4; ni++)
#pragma unroll
        for (int r = 0; r < 4; r++) oacc[st][ni][r] *= alpha[r];

#pragma unroll
      for (int ks = 0; ks < 2; ks++) {
        const int g = (ks * 4 + quad) ^ (l15 & 7);
        short8 pf = *(const short8*)&myPs[l15 * 64 + g * 8];
#pragma unroll
        for (int ni = 0; ni < 4; ni++) {
          short8 vf = *(const short8*)&Vs[(ni * 16 + l15) * 64 + ((ks * 4 + quad) ^ (l15 & 7)) * 8];
          oacc[st][ni] = __builtin_amdgcn_mfma_f32_16x16x32_bf16(pf, vf, oacc[st][ni], 0, 0, 0);
        }
      }
    }
  }

#pragma unroll
  for (int st = 0; st < 2; st++) {
    float inv[4];
#pragma unroll
    for (int r = 0; r < 4; r++) inv[r] = 1.0f / l[st][r];
#pragma unroll
    for (int ni = 0; ni < 4; ni++)
#pragma unroll
      for (int r = 0; r < 4; r++) {
        int row = b * N_ + qt * 128 + st * 64 + wave * 16 + quad * 4 + r;
        int col = h * D_ + ni * 16 + l15;
        o[(size_t)row * C_ + col] = f32_to_bf16(oacc[st][ni][r] * inv[r]);
      }
  }
}

// ---------------- launch ----------------
extern "C" void kernel_launch(void* const* d_in, const int* in_sizes, int n_in,
                              void* d_out, int out_size, void* d_ws, size_t ws_size,
                              hipStream_t stream) {
  const float* x      = (const float*)d_in[0];
  const float* ln1_w  = (const float*)d_in[1];
  const float* ln1_b  = (const float*)d_in[2];
  const float* qkv_w  = (const float*)d_in[3];
  const float* proj_w = (const float*)d_in[4];
  const float* proj_b = (const float*)d_in[5];
  const float* ln2_w  = (const float*)d_in[6];
  const float* ln2_b  = (const float*)d_in[7];
  const float* fc1_w  = (const float*)d_in[8];
  const float* fc1_b  = (const float*)d_in[9];
  const float* fc2_w  = (const float*)d_in[10];
  const float* fc2_b  = (const float*)d_in[11];
  float* out = (float*)d_out;

  char* ws = (char*)d_ws;
  size_t off = 0;
  auto alloc = [&](size_t bytes) { void* p = ws + off; off += (bytes + 255) & ~255ull; return p; };
  u16* wqkv  = (u16*)alloc((size_t)3 * C_ * C_ * 2);
  u16* wproj = (u16*)alloc((size_t)C_ * C_ * 2);
  u16* wfc1  = (u16*)alloc((size_t)HID_ * C_ * 2);
  u16* wfc2  = (u16*)alloc((size_t)C_ * HID_ * 2);
  u16* wbase = wqkv;   // contiguous (all segment sizes are 256B-multiples)
  u16* regionA = (u16*)alloc((size_t)BN_ * HID_ * 2);  // h | qkv, later o, later act
  float* xnew  = (float*)alloc((size_t)BN_ * C_ * 4);
  u16* h2      = (u16*)alloc((size_t)BN_ * C_ * 2);

  u16* hbuf = regionA;                        // [BN, C]   (dead after QKV)
  u16* qkvb = regionA + (size_t)BN_ * C_;     // [BN, 3C]  (dead after attn)
  u16* obuf = regionA;                        // [BN, C]   overwrites hbuf
  u16* act  = regionA;                        // [BN, HID] overwrites qkv+o
  u16* vtbuf = (u16*)xnew;                    // [B*H, D, N] aliases xnew (dead before proj writes)

  cast4_kernel<<<dim3(NW3_ / 256), 256, 0, stream>>>(qkv_w, proj_w, fc1_w, fc2_w, wbase);

  ln_kernel<<<dim3(BN_ / 4), 256, 0, stream>>>(x, ln1_w, ln1_b, hbuf);

  gemm_qkv<<<dim3(3 * C_ / 128, BN_ / 128), 256, 0, stream>>>(hbuf, wqkv, 3 * C_, C_, qkvb);

  transpose_v<<<dim3(N_ / 64, B_ * H_), 256, 0, stream>>>(qkvb, vtbuf);

  attn_kernel<<<dim3((N_ / 128) * B_ * H_), 256, 0, stream>>>(qkvb, vtbuf, obuf);

  gemm_proj2x<<<dim3(C_ / 128, BN_ / 128), 256, 0, stream>>>(obuf, wproj, C_, C_, proj_b, xnew);

  ln_kernel<<<dim3(BN_ / 4), 256, 0, stream>>>(xnew, ln2_w, ln2_b, h2);

  gemm_fc1gelu<<<dim3(HID_ / 128, BN_ / 128), 256, 0, stream>>>(h2, wfc1, HID_, C_, fc1_b, act);

  gemm_fc2res<<<dim3(C_ / 128, BN_ / 128), 256, 0, stream>>>(act, wfc2, C_, HID_, fc2_b, xnew, out);
}